// Round 5
// baseline (384.997 us; speedup 1.0000x reference)
//
#include <hip/hip_runtime.h>
#include <hip/hip_bf16.h>
#include <math.h>

// Problem: B=131072, D=512, C=5, K=10 experts.
// GEMM [B,512] x [512,64pad] bf16 MFMA + per-row softmax/relu epilogue.
// R5: ROW-CONTIGUOUS emb staging (one 2-KB row per wave-pair instruction,
// full DRAM-page granules), bf16-converted into LDS in MFMA A-fragment
// order with XOR-swizzle; K-loop reads A via conflict-free ds_read_b128
// and B from L2-resident global fragment table.
#define BATCH   131072
#define DIM     512
#define NCLS    5
#define NEXP    10
#define NW      60
#define NCOL    64
#define PACK_TPB 256
#define TPB     128            // 2 waves
#define BLOCK_ROWS 32          // 2 wave-tiles of 16 rows
#define NCHUNK  16             // 512 / 32
#define EPS_STRIDE 65

typedef short bf16x8 __attribute__((ext_vector_type(8)));
typedef float f32x4  __attribute__((ext_vector_type(4)));

static __device__ __forceinline__ unsigned short bfb(float f) {
    __hip_bfloat16 h = __float2bfloat16(f);
    return __builtin_bit_cast(unsigned short, h);
}

// ---------------------------------------------------------------------------
// Pack weights into per-lane B-fragment order for mfma_f32_16x16x32_bf16:
// wfrag[((c*4+t)*64+lane)*8+j] = B[k=32c+(lane>>4)*8+j][n=16t+(lane&15)]
// n<10: Wg col n; 10<=n<60: We[(n-10)/5][d][(n-10)%5]; else 0. bpack: biases.
// ---------------------------------------------------------------------------
__global__ void pack_w_kernel(const float* __restrict__ We,
                              const float* __restrict__ be,
                              const float* __restrict__ Wg,
                              const float* __restrict__ bg,
                              unsigned short* __restrict__ wfrag,
                              float* __restrict__ bpack) {
    int idx = blockIdx.x * PACK_TPB + threadIdx.x;   // 0 .. 32767
    int c    = idx >> 11;
    int t    = (idx >> 9) & 3;
    int lane = (idx >> 3) & 63;
    int j    = idx & 7;
    int d = c * 32 + (lane >> 4) * 8 + j;
    int n = t * 16 + (lane & 15);
    float v = 0.0f;
    if (n < NEXP) {
        v = Wg[d * NEXP + n];
    } else if (n < NW) {
        int k  = (n - NEXP) / NCLS;
        int cc = (n - NEXP) % NCLS;
        v = We[(k * DIM + d) * NCLS + cc];
    }
    wfrag[idx] = bfb(v);
    if (idx < NCOL) {
        float bv = 0.0f;
        if (idx < NEXP) bv = bg[idx];
        else if (idx < NW) {
            int k  = (idx - NEXP) / NCLS;
            int cc = (idx - NEXP) % NCLS;
            bv = be[k * NCLS + cc];
        }
        bpack[idx] = bv;
    }
}

// ---------------------------------------------------------------------------
// Main kernel. 2 waves / 32 rows per block.
// Stage: per p=0..31, the 128 threads read row p of the tile (2 KB,
//   fully contiguous), cvt to bf16, ds_write_b64 into fragment-order LDS:
//   logical slot = ((g*16+c)<<6) | (q<<4) | r, phys = slot ^ (c&7).
// Compute: wave w, chunk c: A-frag = ldsA[((w*16+c)<<6) + (L ^ (c&7))]
//   (conflict-free b128), B-frags from global (L2-resident), 4 MFMA/chunk.
// Epilogue: LDS transpose (reuse A region) + per-row softmax/relu/mix.
// ---------------------------------------------------------------------------
__global__ __launch_bounds__(TPB, 2) void moe_mfma_kernel(
        const float* __restrict__ emb,
        const float4* __restrict__ wfrag4,
        const float* __restrict__ bpack,
        float* __restrict__ out) {
    __shared__ uint2 ldsA[4096];   // 32 KB: A-frags (bf16); reused as epilogue buf

    const int tid = threadIdx.x;
    const int w   = tid >> 6;          // wave 0..1
    const int L   = tid & 63;          // lane

    // ---- stage: 32 rows x 2 KB, row-contiguous global reads ----
    const float4* embv = reinterpret_cast<const float4*>(emb);
    const size_t base4 = (size_t)blockIdx.x * (BLOCK_ROWS * DIM / 4);
    const int c_t     = tid >> 3;                  // chunk this thread feeds
    const int colpart = (c_t << 6) + (((tid >> 1) & 3) << 4);
    const int key     = c_t & 7;
    const int jh      = tid & 1;

    #pragma unroll
    for (int batch = 0; batch < 4; ++batch) {
        float4 v[8];
        #pragma unroll
        for (int i = 0; i < 8; ++i) {
            int p = batch * 8 + i;                 // row within tile
            v[i] = embv[base4 + (size_t)p * (DIM / 4) + tid];
        }
        #pragma unroll
        for (int i = 0; i < 8; ++i) {
            int p = batch * 8 + i;
            int g = p >> 4, r = p & 15;
            int slot = (g << 10) + colpart + r;    // ((g*16)<<6) == g<<10
            int phys = slot ^ key;
            uint2 pk;
            pk.x = (unsigned)bfb(v[i].x) | ((unsigned)bfb(v[i].y) << 16);
            pk.y = (unsigned)bfb(v[i].z) | ((unsigned)bfb(v[i].w) << 16);
            ldsA[phys * 2 + jh] = pk;
        }
    }
    __syncthreads();

    // ---- compute: per wave 16 rows x 64 cols ----
    const bf16x8* ap = reinterpret_cast<const bf16x8*>(ldsA);
    const bf16x8* bp = reinterpret_cast<const bf16x8*>(wfrag4);

    f32x4 acc0 = {0.f, 0.f, 0.f, 0.f};
    f32x4 acc1 = acc0, acc2 = acc0, acc3 = acc0;

    #pragma unroll 4
    for (int c = 0; c < NCHUNK; ++c) {
        bf16x8 af = ap[((w * 16 + c) << 6) + (L ^ (c & 7))];
        bf16x8 b0 = bp[((c * 4 + 0) << 6) + L];
        bf16x8 b1 = bp[((c * 4 + 1) << 6) + L];
        bf16x8 b2 = bp[((c * 4 + 2) << 6) + L];
        bf16x8 b3 = bp[((c * 4 + 3) << 6) + L];
        acc0 = __builtin_amdgcn_mfma_f32_16x16x32_bf16(af, b0, acc0, 0, 0, 0);
        acc1 = __builtin_amdgcn_mfma_f32_16x16x32_bf16(af, b1, acc1, 0, 0, 0);
        acc2 = __builtin_amdgcn_mfma_f32_16x16x32_bf16(af, b2, acc2, 0, 0, 0);
        acc3 = __builtin_amdgcn_mfma_f32_16x16x32_bf16(af, b3, acc3, 0, 0, 0);
    }

    // ---- epilogue: reuse A-LDS for C transpose ----
    __syncthreads();                   // all waves done reading A
    float* eps = reinterpret_cast<float*>(ldsA);   // 32 x 65 floats = 8.3 KB
    const int r = L & 15;
    const int q = L >> 4;
    #pragma unroll
    for (int i = 0; i < 4; ++i) {
        int rowl = w * 16 + q * 4 + i;             // C/D: col=lane&15, row=q*4+reg
        eps[rowl * EPS_STRIDE +  0 + r] = acc0[i];
        eps[rowl * EPS_STRIDE + 16 + r] = acc1[i];
        eps[rowl * EPS_STRIDE + 32 + r] = acc2[i];
        eps[rowl * EPS_STRIDE + 48 + r] = acc3[i];
    }
    __syncthreads();

    // one thread per row: softmax(10) + relu + gate-weighted sum -> 5 outputs
    if (tid < BLOCK_ROWS) {
        const float* row = eps + tid * EPS_STRIDE;
        float g[NEXP];
        float m = -INFINITY;
        #pragma unroll
        for (int k = 0; k < NEXP; ++k) {
            g[k] = row[k] + bpack[k];
            m = fmaxf(m, g[k]);
        }
        float s = 0.0f;
        #pragma unroll
        for (int k = 0; k < NEXP; ++k) {
            g[k] = __expf(g[k] - m);
            s += g[k];
        }
        float inv = 1.0f / s;

        float o[NCLS] = {0.f, 0.f, 0.f, 0.f, 0.f};
        #pragma unroll
        for (int k = 0; k < NEXP; ++k) {
            float gk = g[k] * inv;
            #pragma unroll
            for (int cc = 0; cc < NCLS; ++cc) {
                int n = NEXP + k * NCLS + cc;
                float e = row[n] + bpack[n];
                e = fmaxf(e, 0.0f);
                o[cc] = fmaf(gk, e, o[cc]);
            }
        }
        size_t ob = ((size_t)blockIdx.x * BLOCK_ROWS + tid) * NCLS;
        #pragma unroll
        for (int cc = 0; cc < NCLS; ++cc) out[ob + cc] = o[cc];
    }
}

extern "C" void kernel_launch(void* const* d_in, const int* in_sizes, int n_in,
                              void* d_out, int out_size, void* d_ws, size_t ws_size,
                              hipStream_t stream) {
    const float* emb = (const float*)d_in[0];
    const float* We  = (const float*)d_in[1];
    const float* be  = (const float*)d_in[2];
    const float* Wg  = (const float*)d_in[3];
    const float* bg  = (const float*)d_in[4];
    float* out = (float*)d_out;

    unsigned short* wfrag = (unsigned short*)d_ws;            // 64 KB
    float* bpack = (float*)((char*)d_ws + 32768 * sizeof(unsigned short));

    pack_w_kernel<<<(16 * 4 * 64 * 8) / PACK_TPB, PACK_TPB, 0, stream>>>(
        We, be, Wg, bg, wfrag, bpack);
    moe_mfma_kernel<<<BATCH / BLOCK_ROWS, TPB, 0, stream>>>(
        emb, (const float4*)wfrag, bpack, out);
}